// Round 11
// baseline (76.156 us; speedup 1.0000x reference)
//
#include <hip/hip_runtime.h>

#define BS 4
#define NQ 100
#define NT 25
#define NC 81
#define PIX 65536
#define KCHUNK 512
#define NKB (PIX / KCHUNK)       // 128 chunks per batch
#define NQT 7                    // q-tile slots in partial buffer
#define STRY 520                 // LDS y row stride in ushorts (1040 B)

// ws layout (floats)
#define WS_SP 0                          // BS*NQ = 400
#define WS_SG 400                        // BS*NQ = 400
#define WS_YT 800                        // BS*NT = 100
#define WS_P0 1024                       // xy partials
#define PSZ   (BS * NQT * NKB * 400)     // 1,433,600 floats
#define WS_P1 (WS_P0 + PSZ)

typedef __attribute__((ext_vector_type(8))) short bf16x8;
typedef __attribute__((ext_vector_type(4))) float f32x4;

__device__ __forceinline__ float4 ld4(const float* p) {
    return *reinterpret_cast<const float4*>(p);
}
__device__ __forceinline__ f32x4 mfma16(bf16x8 a, bf16x8 b, f32x4 c) {
    return __builtin_amdgcn_mfma_f32_16x16x32_bf16(a, b, c, 0, 0, 0);
}
// truncation pack: two f32 -> two bf16 in one u32 (1 op)
__device__ __forceinline__ unsigned pack2t(float lo, float hi) {
#if __has_builtin(__builtin_amdgcn_perm)
    return __builtin_amdgcn_perm(__float_as_uint(hi), __float_as_uint(lo), 0x07060302u);
#else
    return (__float_as_uint(hi) & 0xFFFF0000u) | (__float_as_uint(lo) >> 16);
#endif
}
// round-half-up pack (y staging only)
__device__ __forceinline__ unsigned pack2r(float lo, float hi) {
#if __has_builtin(__builtin_amdgcn_perm)
    return __builtin_amdgcn_perm(__float_as_uint(hi) + 0x8000u,
                                 __float_as_uint(lo) + 0x8000u, 0x07060302u);
#else
    return (((__float_as_uint(hi) + 0x8000u) & 0xFFFF0000u) |
            ((__float_as_uint(lo) + 0x8000u) >> 16));
#endif
}

union frag_u { unsigned u[4]; bf16x8 v; };

__global__ __launch_bounds__(256) void partial_kernel(
    const float* __restrict__ pm,   // [BS,NQ,PIX] mask logits
    const float* __restrict__ tm,   // [BS,NT,PIX] target masks
    float* __restrict__ ws)
{
    __shared__ unsigned short ys[32 * STRY];   // 33.3 KB

    const int tid = threadIdx.x;
    const int bid = blockIdx.x;
    const int chunk = bid & (NKB - 1);
    const int rest = bid >> 7;       // 0..7
    const int qg = rest & 1;
    const int b = rest >> 1;
    const int kbase = chunk * KCHUNK;

    // ---- stage y chunk (rows 0..24) as bf16; rows 25..31 zeroed ----
    {
        const float* yg = tm + (size_t)b * NT * PIX + kbase;
        for (int j = tid; j < 32 * (KCHUNK / 4); j += 256) {
            const int row = j >> 7, c = j & 127;
            uint2 w = make_uint2(0u, 0u);
            if (row < NT) {
                const float4 v = ld4(yg + (size_t)row * PIX + c * 4);
                w.x = pack2r(v.x, v.y);
                w.y = pack2r(v.z, v.w);
            }
            *reinterpret_cast<uint2*>(&ys[row * STRY + c * 4]) = w;
        }
    }
    __syncthreads();

    const int l = tid & 63;
    const int wv = tid >> 6;
    const int qt = qg * 4 + wv;              // 0..7
    const bool ones_wave = (qt == 7);        // rows 112..127: all invalid -> Sum(y) duty
    const int lrow = l & 15;
    const int lk = (l >> 4) * 8;             // px offset of this lane's 8 elements

    const int q = qt * 16 + lrow;
    const bool qv = (q < NQ);

    const float* xp = pm + (size_t)(b * NQ + (qv ? q : 0)) * PIX + kbase + lk;

    f32x4 cxy[2] = {};
    f32x4 csy[2] = {};
    f32x4 cxs = {};     // row sums of x    (B = ones)
    f32x4 css = {};     // row sums of sig  (B = ones)
    float l2 = 0.f;

    frag_u fones;
    fones.u[0] = fones.u[1] = fones.u[2] = fones.u[3] = 0x3F803F80u;  // bf16 1.0 x2

    // ---- 3-deep x prefetch ring ----
    float4 Xa[3], Xb[3];
    if (!ones_wave) {
        Xa[0] = ld4(xp);      Xb[0] = ld4(xp + 4);
        Xa[1] = ld4(xp + 32); Xb[1] = ld4(xp + 36);
        Xa[2] = ld4(xp + 64); Xb[2] = ld4(xp + 68);
    }

    // ---- LDS y-frag prefetch, 1 k-step ahead ----
    bf16x8 by0 = *reinterpret_cast<const bf16x8*>(&ys[lrow * STRY + lk]);
    bf16x8 by1 = *reinterpret_cast<const bf16x8*>(&ys[(16 + lrow) * STRY + lk]);

    #pragma unroll
    for (int kb = 0; kb < KCHUNK / 32; ++kb) {
        bf16x8 nb0, nb1;
        if (kb < KCHUNK / 32 - 1) {
            const int ko = (kb + 1) * 32;
            nb0 = *reinterpret_cast<const bf16x8*>(&ys[lrow * STRY + ko + lk]);
            nb1 = *reinterpret_cast<const bf16x8*>(&ys[(16 + lrow) * STRY + ko + lk]);
        }

        frag_u fx, fs;
        if (!ones_wave) {
            const int slot = kb % 3;
            const float4 xa = Xa[slot], xb = Xb[slot];
            if (kb < KCHUNK / 32 - 3) {
                const int ko = (kb + 3) * 32;
                Xa[slot] = ld4(xp + ko);
                Xb[slot] = ld4(xp + ko + 4);
            }
            // r = sigmoid(x) = 1/(1+e^{-x})
            // sum softplus = sum x - ln2 * log2(prod r)   (one log per 8 elems)
            const float xe[8] = {xa.x, xa.y, xa.z, xa.w, xb.x, xb.y, xb.z, xb.w};
            float rg[8];
            float pr = 1.0f;
            #pragma unroll
            for (int e = 0; e < 8; ++e) {
                const float x = xe[e];
                const float ex = __expf(-x);
                const float r = __builtin_amdgcn_rcpf(1.0f + ex);
                rg[e] = r;
                pr *= r;          // prod of 8 sigmoids: >= ~1e-35 for |x|<~10
            }
            l2 += __log2f(pr);    // garbage on invalid-q lanes: filtered at atomic
            #pragma unroll
            for (int e = 0; e < 4; ++e) {
                fx.u[e] = pack2t(xe[2 * e], xe[2 * e + 1]);
                fs.u[e] = pack2t(rg[2 * e], rg[2 * e + 1]);
            }
        } else {
            fx = fones; fs = fones;
        }

        cxy[0] = mfma16(fx.v, by0, cxy[0]);
        cxy[1] = mfma16(fx.v, by1, cxy[1]);
        csy[0] = mfma16(fs.v, by0, csy[0]);
        csy[1] = mfma16(fs.v, by1, csy[1]);
        if (!ones_wave) {
            cxs = mfma16(fx.v, fones.v, cxs);   // Sum_k x  per q-row (all cols equal)
            css = mfma16(fs.v, fones.v, css);   // Sum_k sig per q-row
        }

        if (kb < KCHUNK / 32 - 1) { by0 = nb0; by1 = nb1; }
    }

    if (!ones_wave) {
        // ---- C partials -> plain stores (C/D map: col=lane&15, row=(lane>>4)*4+reg) ----
        const size_t slot = ((size_t)(b * NQT + qt) * NKB + chunk) * 400;
        float* px = ws + WS_P0 + slot;
        float* ps = ws + WS_P1 + slot;
        #pragma unroll
        for (int n = 0; n < 2; ++n) {
            const int t = n * 16 + lrow;
            if (t < NT) {
                #pragma unroll
                for (int r = 0; r < 4; ++r) {
                    const int qr = (l >> 4) * 4 + r;
                    px[qr * NT + t] = cxy[n][r];
                    ps[qr * NT + t] = csy[n][r];
                }
            }
        }
        // ---- softplus log-part: lanes {l, l+16, l+32, l+48} share one q ----
        l2 += __shfl_xor(l2, 16); l2 += __shfl_xor(l2, 32);
        if (l < 16 && qv) {
            atomicAdd(&ws[WS_SP + b * NQ + q], -0.69314718056f * l2);
        }
        // ---- Sx / Ssig from ones-MFMA: col 0 lanes carry all 16 q-rows ----
        if ((l & 15) == 0) {
            #pragma unroll
            for (int r = 0; r < 4; ++r) {
                const int qq = qt * 16 + (l >> 4) * 4 + r;
                if (qq < NQ) {
                    atomicAdd(&ws[WS_SP + b * NQ + qq], cxs[r]);
                    atomicAdd(&ws[WS_SG + b * NQ + qq], css[r]);
                }
            }
        }
    } else {
        // A == ones  ->  every C row = sum_k y[t]; reg 0 of lanes 0..15
        if (l < 16) atomicAdd(&ws[WS_YT + b * NT + l], cxy[0][0]);
        if (l < NT - 16) atomicAdd(&ws[WS_YT + b * NT + 16 + l], cxy[1][0]);
    }
}

__global__ __launch_bounds__(256) void finalize_kernel(
    const float* __restrict__ logits,  // [BS,NQ,NC]
    const int* __restrict__ labels,    // [BS,NT]
    const float* __restrict__ ws,
    float* __restrict__ out)           // [BS,NQ,NT]
{
    __shared__ float s1[256];
    __shared__ float s2[256];

    const int row = blockIdx.x;        // b*NQ + q
    const int b = row / NQ, q = row % NQ;
    const int qt = q / 16, qr = q % 16;
    const int tid = threadIdx.x;
    const int t = tid & 31, cg = tid >> 5;     // 8 chunk-groups

    float sxy = 0.f, ssy = 0.f;
    if (t < NT) {
        const size_t base = ((size_t)(b * NQT + qt) * NKB) * 400 + (size_t)qr * NT + t;
        const float* px = ws + WS_P0 + base;
        const float* ps = ws + WS_P1 + base;
        #pragma unroll 4
        for (int k = 0; k < NKB / 8; ++k) {
            const size_t o = (size_t)(cg + 8 * k) * 400;
            sxy += px[o];
            ssy += ps[o];
        }
    }
    s1[tid] = sxy;
    s2[tid] = ssy;
    __syncthreads();

    if (tid < 64) {
        const float* lg = logits + (size_t)row * NC;
        float v0 = (tid < NC) ? lg[tid] : -1e30f;
        float v1 = (tid + 64 < NC) ? lg[tid + 64] : -1e30f;
        float mx = fmaxf(v0, v1);
        #pragma unroll
        for (int off = 32; off; off >>= 1) mx = fmaxf(mx, __shfl_xor(mx, off, 64));
        float e = ((tid < NC) ? __expf(v0 - mx) : 0.f) +
                  ((tid + 64 < NC) ? __expf(v1 - mx) : 0.f);
        #pragma unroll
        for (int off = 32; off; off >>= 1) e += __shfl_xor(e, off, 64);

        if (tid < NT) {
            float xy = 0.f, sy = 0.f;
            #pragma unroll
            for (int g = 0; g < 8; ++g) { xy += s1[g * 32 + tid]; sy += s2[g * 32 + tid]; }

            const int lab = labels[b * NT + tid];
            const float prob = __expf(lg[lab] - mx) / e;
            const float inv_p = 1.0f / (float)PIX;
            const float bce = ws[WS_SP + row] * inv_p - xy * inv_p;
            const float dice = 1.0f - 2.0f * sy /
                               (ws[WS_SG + row] + ws[WS_YT + b * NT + tid] + 1e-6f);
            out[(size_t)row * NT + tid] = -prob + bce + dice;
        }
    }
}

extern "C" void kernel_launch(void* const* d_in, const int* in_sizes, int n_in,
                              void* d_out, int out_size, void* d_ws, size_t ws_size,
                              hipStream_t stream) {
    const float* pred_logits = (const float*)d_in[0];
    const float* pred_masks  = (const float*)d_in[1];
    const int*   tgt_labels  = (const int*)d_in[2];
    const float* tgt_masks   = (const float*)d_in[3];
    float* out = (float*)d_out;
    float* ws  = (float*)d_ws;

    hipMemsetAsync(d_ws, 0, 1024 * sizeof(float), stream);

    // grid: 128 chunks x (2 q-groups) x 4 batches = 1024 blocks of 4 waves
    partial_kernel<<<BS * 2 * NKB, 256, 0, stream>>>(pred_masks, tgt_masks, ws);
    finalize_kernel<<<BS * NQ, 256, 0, stream>>>(pred_logits, tgt_labels, ws, out);
}

// Round 12
// 48.752 us; speedup vs baseline: 1.5621x; 1.5621x over previous
//
#include <hip/hip_runtime.h>

#define BS 4
#define NQ 100
#define NT 25
#define NC 81
#define PIX 65536
#define KCHUNK 512
#define NKB (PIX / KCHUNK)       // 128 chunks per batch
#define NQT 7                    // q-tile slots in partial buffer
#define STRY 520                 // LDS y row stride in ushorts (1040 B)

// ws layout (floats)
#define WS_SP 0                          // BS*NQ = 400
#define WS_SG 400                        // BS*NQ = 400
#define WS_YT 800                        // BS*NT = 100
#define WS_P0 1024                       // xy partials
#define PSZ   (BS * NQT * NKB * 400)     // 1,433,600 floats
#define WS_P1 (WS_P0 + PSZ)

typedef __attribute__((ext_vector_type(8))) short bf16x8;
typedef __attribute__((ext_vector_type(4))) float f32x4;

__device__ __forceinline__ float4 ld4(const float* p) {
    return *reinterpret_cast<const float4*>(p);
}
__device__ __forceinline__ f32x4 mfma16(bf16x8 a, bf16x8 b, f32x4 c) {
    return __builtin_amdgcn_mfma_f32_16x16x32_bf16(a, b, c, 0, 0, 0);
}
// truncation pack: two f32 -> two bf16 in one u32 (1 op)
__device__ __forceinline__ unsigned pack2t(float lo, float hi) {
#if __has_builtin(__builtin_amdgcn_perm)
    return __builtin_amdgcn_perm(__float_as_uint(hi), __float_as_uint(lo), 0x07060302u);
#else
    return (__float_as_uint(hi) & 0xFFFF0000u) | (__float_as_uint(lo) >> 16);
#endif
}
// round-half-up pack (y staging only)
__device__ __forceinline__ unsigned pack2r(float lo, float hi) {
#if __has_builtin(__builtin_amdgcn_perm)
    return __builtin_amdgcn_perm(__float_as_uint(hi) + 0x8000u,
                                 __float_as_uint(lo) + 0x8000u, 0x07060302u);
#else
    return (((__float_as_uint(hi) + 0x8000u) & 0xFFFF0000u) |
            ((__float_as_uint(lo) + 0x8000u) >> 16));
#endif
}

union frag_u { unsigned u[4]; bf16x8 v; };

__global__ __launch_bounds__(256) void partial_kernel(
    const float* __restrict__ pm,   // [BS,NQ,PIX] mask logits
    const float* __restrict__ tm,   // [BS,NT,PIX] target masks
    float* __restrict__ ws)
{
    __shared__ unsigned short ys[32 * STRY];   // 33.3 KB

    const int tid = threadIdx.x;
    const int bid = blockIdx.x;
    const int chunk = bid & (NKB - 1);
    const int rest = bid >> 7;       // 0..7
    const int qg = rest & 1;
    const int b = rest >> 1;
    const int kbase = chunk * KCHUNK;

    const int l = tid & 63;
    const int wv = tid >> 6;
    const int qt = qg * 4 + wv;              // 0..7
    const bool ones_wave = (qt == 7);        // rows 112..127: all invalid -> Sum(y) duty
    const int lrow = l & 15;
    const int lk = (l >> 4) * 8;             // px offset of this lane's 8 elements

    const int q = qt * 16 + lrow;
    const bool qv = (q < NQ);

    const float* xp = pm + (size_t)(b * NQ + (qv ? q : 0)) * PIX + kbase + lk;

    // ---- T14 issue-early: start the x prefetch ring BEFORE y staging so the
    // warm-up HBM round-trip overlaps the staging loads (barrier drains vmcnt
    // anyway, so these are simply complete when the k-loop starts) ----
    float4 Xa[2], Xb[2];
    if (!ones_wave) {
        Xa[0] = ld4(xp);      Xb[0] = ld4(xp + 4);
        Xa[1] = ld4(xp + 32); Xb[1] = ld4(xp + 36);
    }

    // ---- stage y chunk (rows 0..24) as bf16; rows 25..31 zeroed ----
    {
        const float* yg = tm + (size_t)b * NT * PIX + kbase;
        for (int j = tid; j < 32 * (KCHUNK / 4); j += 256) {
            const int row = j >> 7, c = j & 127;
            uint2 w = make_uint2(0u, 0u);
            if (row < NT) {
                const float4 v = ld4(yg + (size_t)row * PIX + c * 4);
                w.x = pack2r(v.x, v.y);
                w.y = pack2r(v.z, v.w);
            }
            *reinterpret_cast<uint2*>(&ys[row * STRY + c * 4]) = w;
        }
    }
    __syncthreads();

    f32x4 cxy[2] = {};
    f32x4 csy[2] = {};
    float sx = 0.f, sg = 0.f, l2 = 0.f;

    frag_u fones;
    fones.u[0] = fones.u[1] = fones.u[2] = fones.u[3] = 0x3F803F80u;  // bf16 1.0 x2

    // ---- LDS y-frag prefetch, 1 k-step ahead ----
    bf16x8 by0 = *reinterpret_cast<const bf16x8*>(&ys[lrow * STRY + lk]);
    bf16x8 by1 = *reinterpret_cast<const bf16x8*>(&ys[(16 + lrow) * STRY + lk]);

    #pragma unroll
    for (int kb = 0; kb < KCHUNK / 32; ++kb) {
        bf16x8 nb0, nb1;
        if (kb < KCHUNK / 32 - 1) {
            const int ko = (kb + 1) * 32;
            nb0 = *reinterpret_cast<const bf16x8*>(&ys[lrow * STRY + ko + lk]);
            nb1 = *reinterpret_cast<const bf16x8*>(&ys[(16 + lrow) * STRY + ko + lk]);
        }

        frag_u fx, fs;
        if (!ones_wave) {
            const float4 xa = Xa[kb & 1], xb = Xb[kb & 1];
            if (kb < KCHUNK / 32 - 2) {
                const int ko = (kb + 2) * 32;
                Xa[kb & 1] = ld4(xp + ko);
                Xb[kb & 1] = ld4(xp + ko + 4);
            }
            // r = sigmoid(x) = 1/(1+e^{-x})
            // sum softplus = sum x - ln2 * log2(prod r)   (one log per 8 elems)
            const float xe[8] = {xa.x, xa.y, xa.z, xa.w, xb.x, xb.y, xb.z, xb.w};
            float rg[8];
            float pr = 1.0f;
            #pragma unroll
            for (int e = 0; e < 8; ++e) {
                const float x = xe[e];
                const float ex = __expf(-x);
                const float r = __builtin_amdgcn_rcpf(1.0f + ex);
                rg[e] = r;
                pr *= r;          // prod of 8 sigmoids: >= ~1e-35 for |x|<~10
                sx += x;
                sg += r;          // garbage on invalid-q lanes: filtered at atomic
            }
            l2 += __log2f(pr);
            #pragma unroll
            for (int e = 0; e < 4; ++e) {
                fx.u[e] = pack2t(xe[2 * e], xe[2 * e + 1]);
                fs.u[e] = pack2t(rg[2 * e], rg[2 * e + 1]);
            }
        } else {
            fx = fones; fs = fones;
        }

        cxy[0] = mfma16(fx.v, by0, cxy[0]);
        cxy[1] = mfma16(fx.v, by1, cxy[1]);
        csy[0] = mfma16(fs.v, by0, csy[0]);
        csy[1] = mfma16(fs.v, by1, csy[1]);

        if (kb < KCHUNK / 32 - 1) { by0 = nb0; by1 = nb1; }
    }

    if (!ones_wave) {
        // ---- C partials -> plain stores (C/D map: col=lane&15, row=(lane>>4)*4+reg) ----
        const size_t slot = ((size_t)(b * NQT + qt) * NKB + chunk) * 400;
        float* px = ws + WS_P0 + slot;
        float* ps = ws + WS_P1 + slot;
        #pragma unroll
        for (int n = 0; n < 2; ++n) {
            const int t = n * 16 + lrow;
            if (t < NT) {
                #pragma unroll
                for (int r = 0; r < 4; ++r) {
                    const int qr = (l >> 4) * 4 + r;
                    px[qr * NT + t] = cxy[n][r];
                    ps[qr * NT + t] = csy[n][r];
                }
            }
        }
        // ---- row sums: lanes {l, l+16, l+32, l+48} share one q ----
        sx += __shfl_xor(sx, 16); sx += __shfl_xor(sx, 32);
        l2 += __shfl_xor(l2, 16); l2 += __shfl_xor(l2, 32);
        sg += __shfl_xor(sg, 16); sg += __shfl_xor(sg, 32);
        if (l < 16 && qv) {
            atomicAdd(&ws[WS_SP + b * NQ + q], sx - 0.69314718056f * l2);
            atomicAdd(&ws[WS_SG + b * NQ + q], sg);
        }
    } else {
        // A == ones  ->  every C row = sum_k y[t]; reg 0 of lanes 0..15
        if (l < 16) atomicAdd(&ws[WS_YT + b * NT + l], cxy[0][0]);
        if (l < NT - 16) atomicAdd(&ws[WS_YT + b * NT + 16 + l], cxy[1][0]);
    }
}

__global__ __launch_bounds__(256) void finalize_kernel(
    const float* __restrict__ logits,  // [BS,NQ,NC]
    const int* __restrict__ labels,    // [BS,NT]
    const float* __restrict__ ws,
    float* __restrict__ out)           // [BS,NQ,NT]
{
    __shared__ float s1[256];
    __shared__ float s2[256];

    const int row = blockIdx.x;        // b*NQ + q
    const int b = row / NQ, q = row % NQ;
    const int qt = q / 16, qr = q % 16;
    const int tid = threadIdx.x;
    const int t = tid & 31, cg = tid >> 5;     // 8 chunk-groups

    float sxy = 0.f, ssy = 0.f;
    if (t < NT) {
        const size_t base = ((size_t)(b * NQT + qt) * NKB) * 400 + (size_t)qr * NT + t;
        const float* px = ws + WS_P0 + base;
        const float* ps = ws + WS_P1 + base;
        #pragma unroll 4
        for (int k = 0; k < NKB / 8; ++k) {
            const size_t o = (size_t)(cg + 8 * k) * 400;
            sxy += px[o];
            ssy += ps[o];
        }
    }
    s1[tid] = sxy;
    s2[tid] = ssy;
    __syncthreads();

    if (tid < 64) {
        const float* lg = logits + (size_t)row * NC;
        float v0 = (tid < NC) ? lg[tid] : -1e30f;
        float v1 = (tid + 64 < NC) ? lg[tid + 64] : -1e30f;
        float mx = fmaxf(v0, v1);
        #pragma unroll
        for (int off = 32; off; off >>= 1) mx = fmaxf(mx, __shfl_xor(mx, off, 64));
        float e = ((tid < NC) ? __expf(v0 - mx) : 0.f) +
                  ((tid + 64 < NC) ? __expf(v1 - mx) : 0.f);
        #pragma unroll
        for (int off = 32; off; off >>= 1) e += __shfl_xor(e, off, 64);

        if (tid < NT) {
            float xy = 0.f, sy = 0.f;
            #pragma unroll
            for (int g = 0; g < 8; ++g) { xy += s1[g * 32 + tid]; sy += s2[g * 32 + tid]; }

            const int lab = labels[b * NT + tid];
            const float prob = __expf(lg[lab] - mx) / e;
            const float inv_p = 1.0f / (float)PIX;
            const float bce = ws[WS_SP + row] * inv_p - xy * inv_p;
            const float dice = 1.0f - 2.0f * sy /
                               (ws[WS_SG + row] + ws[WS_YT + b * NT + tid] + 1e-6f);
            out[(size_t)row * NT + tid] = -prob + bce + dice;
        }
    }
}

extern "C" void kernel_launch(void* const* d_in, const int* in_sizes, int n_in,
                              void* d_out, int out_size, void* d_ws, size_t ws_size,
                              hipStream_t stream) {
    const float* pred_logits = (const float*)d_in[0];
    const float* pred_masks  = (const float*)d_in[1];
    const int*   tgt_labels  = (const int*)d_in[2];
    const float* tgt_masks   = (const float*)d_in[3];
    float* out = (float*)d_out;
    float* ws  = (float*)d_ws;

    hipMemsetAsync(d_ws, 0, 1024 * sizeof(float), stream);

    // grid: 128 chunks x (2 q-groups) x 4 batches = 1024 blocks of 4 waves
    partial_kernel<<<BS * 2 * NKB, 256, 0, stream>>>(pred_masks, tgt_masks, ws);
    finalize_kernel<<<BS * NQ, 256, 0, stream>>>(pred_logits, tgt_labels, ws, out);
}

// Round 13
// 47.054 us; speedup vs baseline: 1.6185x; 1.0361x over previous
//
#include <hip/hip_runtime.h>

#define BS 4
#define NQ 100
#define NT 25
#define NC 81
#define PIX 65536
#define KCHUNK 512
#define NKB (PIX / KCHUNK)       // 128 chunks per batch
#define NQT 7                    // q-tile slots in partial buffer
#define STRY 520                 // LDS y row stride in ushorts (1040 B)

// ws layout (floats)
#define WS_SP 0                          // BS*NQ = 400
#define WS_SG 400                        // BS*NQ = 400
#define WS_YT 800                        // BS*NT = 100
#define WS_P0 1024                       // xy partials
#define PSZ   (BS * NQT * NKB * 400)     // 1,433,600 floats
#define WS_P1 (WS_P0 + PSZ)

typedef __attribute__((ext_vector_type(8))) short bf16x8;
typedef __attribute__((ext_vector_type(4))) float f32x4;

__device__ __forceinline__ float4 ld4(const float* p) {
    return *reinterpret_cast<const float4*>(p);
}
__device__ __forceinline__ f32x4 mfma16(bf16x8 a, bf16x8 b, f32x4 c) {
    return __builtin_amdgcn_mfma_f32_16x16x32_bf16(a, b, c, 0, 0, 0);
}
// truncation pack: two f32 -> two bf16 in one u32 (1 op)
__device__ __forceinline__ unsigned pack2t(float lo, float hi) {
#if __has_builtin(__builtin_amdgcn_perm)
    return __builtin_amdgcn_perm(__float_as_uint(hi), __float_as_uint(lo), 0x07060302u);
#else
    return (__float_as_uint(hi) & 0xFFFF0000u) | (__float_as_uint(lo) >> 16);
#endif
}
// round-half-up pack (y staging only)
__device__ __forceinline__ unsigned pack2r(float lo, float hi) {
#if __has_builtin(__builtin_amdgcn_perm)
    return __builtin_amdgcn_perm(__float_as_uint(hi) + 0x8000u,
                                 __float_as_uint(lo) + 0x8000u, 0x07060302u);
#else
    return (((__float_as_uint(hi) + 0x8000u) & 0xFFFF0000u) |
            ((__float_as_uint(lo) + 0x8000u) >> 16));
#endif
}

union frag_u { unsigned u[4]; bf16x8 v; };

__global__ __launch_bounds__(256) void partial_kernel(
    const float* __restrict__ pm,   // [BS,NQ,PIX] mask logits
    const float* __restrict__ tm,   // [BS,NT,PIX] target masks
    float* __restrict__ ws)
{
    // Only 25 real rows. by1 lanes with lrow>=9 would address rows 25..31;
    // their MFMA columns (t=25..31) are discarded at the C-store, so they
    // read a clamped valid row instead of zero-padding (saves 7 rows of LDS:
    // 33.3 -> 26.0 KB => 6 blocks/CU instead of 4).
    __shared__ unsigned short ys[NT * STRY];   // 26.0 KB

    const int tid = threadIdx.x;
    const int bid = blockIdx.x;
    const int chunk = bid & (NKB - 1);
    const int rest = bid >> 7;       // 0..7
    const int qg = rest & 1;
    const int b = rest >> 1;
    const int kbase = chunk * KCHUNK;

    // ---- stage y chunk (25 rows) as bf16 ----
    {
        const float* yg = tm + (size_t)b * NT * PIX + kbase;
        for (int j = tid; j < NT * (KCHUNK / 4); j += 256) {
            const int row = j >> 7, c = j & 127;
            const float4 v = ld4(yg + (size_t)row * PIX + c * 4);
            uint2 w;
            w.x = pack2r(v.x, v.y);
            w.y = pack2r(v.z, v.w);
            *reinterpret_cast<uint2*>(&ys[row * STRY + c * 4]) = w;
        }
    }
    __syncthreads();

    const int l = tid & 63;
    const int wv = tid >> 6;
    const int qt = qg * 4 + wv;              // 0..7
    const bool ones_wave = (qt == 7);        // rows 112..127: all invalid -> Sum(y) duty
    const int lrow = l & 15;
    const int lk = (l >> 4) * 8;             // px offset of this lane's 8 elements
    const int r1 = (lrow < NT - 16) ? (16 + lrow) : lrow;   // clamped by1 row

    const int q = qt * 16 + lrow;
    const bool qv = (q < NQ);

    const float* xp = pm + (size_t)(b * NQ + (qv ? q : 0)) * PIX + kbase + lk;

    f32x4 cxy[2] = {};
    f32x4 csy[2] = {};
    float sx = 0.f, sg = 0.f, l2 = 0.f;

    frag_u fones;
    fones.u[0] = fones.u[1] = fones.u[2] = fones.u[3] = 0x3F803F80u;  // bf16 1.0 x2

    // ---- 2-deep x prefetch ring ----
    float4 Xa[2], Xb[2];
    if (!ones_wave) {
        Xa[0] = ld4(xp);      Xb[0] = ld4(xp + 4);
        Xa[1] = ld4(xp + 32); Xb[1] = ld4(xp + 36);
    }

    // ---- LDS y-frag prefetch, 1 k-step ahead ----
    bf16x8 by0 = *reinterpret_cast<const bf16x8*>(&ys[lrow * STRY + lk]);
    bf16x8 by1 = *reinterpret_cast<const bf16x8*>(&ys[r1 * STRY + lk]);

    #pragma unroll
    for (int kb = 0; kb < KCHUNK / 32; ++kb) {
        bf16x8 nb0, nb1;
        if (kb < KCHUNK / 32 - 1) {
            const int ko = (kb + 1) * 32;
            nb0 = *reinterpret_cast<const bf16x8*>(&ys[lrow * STRY + ko + lk]);
            nb1 = *reinterpret_cast<const bf16x8*>(&ys[r1 * STRY + ko + lk]);
        }

        frag_u fx, fs;
        if (!ones_wave) {
            const float4 xa = Xa[kb & 1], xb = Xb[kb & 1];
            if (kb < KCHUNK / 32 - 2) {
                const int ko = (kb + 2) * 32;
                Xa[kb & 1] = ld4(xp + ko);
                Xb[kb & 1] = ld4(xp + ko + 4);
            }
            // r = sigmoid(x) = 1/(1+e^{-x})
            // sum softplus = sum x - ln2 * log2(prod r)   (one log per 8 elems)
            const float xe[8] = {xa.x, xa.y, xa.z, xa.w, xb.x, xb.y, xb.z, xb.w};
            float rg[8];
            float pr = 1.0f;
            #pragma unroll
            for (int e = 0; e < 8; ++e) {
                const float x = xe[e];
                const float ex = __expf(-x);
                const float r = __builtin_amdgcn_rcpf(1.0f + ex);
                rg[e] = r;
                pr *= r;          // prod of 8 sigmoids: >= ~1e-35 for |x|<~10
                sx += x;
                sg += r;          // garbage on invalid-q lanes: filtered at atomic
            }
            l2 += __log2f(pr);
            #pragma unroll
            for (int e = 0; e < 4; ++e) {
                fx.u[e] = pack2t(xe[2 * e], xe[2 * e + 1]);
                fs.u[e] = pack2t(rg[2 * e], rg[2 * e + 1]);
            }
        } else {
            fx = fones; fs = fones;
        }

        cxy[0] = mfma16(fx.v, by0, cxy[0]);
        cxy[1] = mfma16(fx.v, by1, cxy[1]);
        csy[0] = mfma16(fs.v, by0, csy[0]);
        csy[1] = mfma16(fs.v, by1, csy[1]);

        if (kb < KCHUNK / 32 - 1) { by0 = nb0; by1 = nb1; }
    }

    if (!ones_wave) {
        // ---- C partials -> plain stores (C/D map: col=lane&15, row=(lane>>4)*4+reg) ----
        const size_t slot = ((size_t)(b * NQT + qt) * NKB + chunk) * 400;
        float* px = ws + WS_P0 + slot;
        float* ps = ws + WS_P1 + slot;
        #pragma unroll
        for (int n = 0; n < 2; ++n) {
            const int t = n * 16 + lrow;
            if (t < NT) {
                #pragma unroll
                for (int r = 0; r < 4; ++r) {
                    const int qr = (l >> 4) * 4 + r;
                    px[qr * NT + t] = cxy[n][r];
                    ps[qr * NT + t] = csy[n][r];
                }
            }
        }
        // ---- row sums: lanes {l, l+16, l+32, l+48} share one q ----
        sx += __shfl_xor(sx, 16); sx += __shfl_xor(sx, 32);
        l2 += __shfl_xor(l2, 16); l2 += __shfl_xor(l2, 32);
        sg += __shfl_xor(sg, 16); sg += __shfl_xor(sg, 32);
        if (l < 16 && qv) {
            atomicAdd(&ws[WS_SP + b * NQ + q], sx - 0.69314718056f * l2);
            atomicAdd(&ws[WS_SG + b * NQ + q], sg);
        }
    } else {
        // A == ones  ->  every C row = sum_k y[t]; reg 0 of lanes 0..15
        if (l < 16) atomicAdd(&ws[WS_YT + b * NT + l], cxy[0][0]);
        if (l < NT - 16) atomicAdd(&ws[WS_YT + b * NT + 16 + l], cxy[1][0]);
    }
}

__global__ __launch_bounds__(256) void finalize_kernel(
    const float* __restrict__ logits,  // [BS,NQ,NC]
    const int* __restrict__ labels,    // [BS,NT]
    const float* __restrict__ ws,
    float* __restrict__ out)           // [BS,NQ,NT]
{
    __shared__ float s1[256];
    __shared__ float s2[256];

    const int row = blockIdx.x;        // b*NQ + q
    const int b = row / NQ, q = row % NQ;
    const int qt = q / 16, qr = q % 16;
    const int tid = threadIdx.x;
    const int t = tid & 31, cg = tid >> 5;     // 8 chunk-groups

    float sxy = 0.f, ssy = 0.f;
    if (t < NT) {
        const size_t base = ((size_t)(b * NQT + qt) * NKB) * 400 + (size_t)qr * NT + t;
        const float* px = ws + WS_P0 + base;
        const float* ps = ws + WS_P1 + base;
        #pragma unroll 4
        for (int k = 0; k < NKB / 8; ++k) {
            const size_t o = (size_t)(cg + 8 * k) * 400;
            sxy += px[o];
            ssy += ps[o];
        }
    }
    s1[tid] = sxy;
    s2[tid] = ssy;
    __syncthreads();

    if (tid < 64) {
        const float* lg = logits + (size_t)row * NC;
        float v0 = (tid < NC) ? lg[tid] : -1e30f;
        float v1 = (tid + 64 < NC) ? lg[tid + 64] : -1e30f;
        float mx = fmaxf(v0, v1);
        #pragma unroll
        for (int off = 32; off; off >>= 1) mx = fmaxf(mx, __shfl_xor(mx, off, 64));
        float e = ((tid < NC) ? __expf(v0 - mx) : 0.f) +
                  ((tid + 64 < NC) ? __expf(v1 - mx) : 0.f);
        #pragma unroll
        for (int off = 32; off; off >>= 1) e += __shfl_xor(e, off, 64);

        if (tid < NT) {
            float xy = 0.f, sy = 0.f;
            #pragma unroll
            for (int g = 0; g < 8; ++g) { xy += s1[g * 32 + tid]; sy += s2[g * 32 + tid]; }

            const int lab = labels[b * NT + tid];
            const float prob = __expf(lg[lab] - mx) / e;
            const float inv_p = 1.0f / (float)PIX;
            const float bce = ws[WS_SP + row] * inv_p - xy * inv_p;
            const float dice = 1.0f - 2.0f * sy /
                               (ws[WS_SG + row] + ws[WS_YT + b * NT + tid] + 1e-6f);
            out[(size_t)row * NT + tid] = -prob + bce + dice;
        }
    }
}

extern "C" void kernel_launch(void* const* d_in, const int* in_sizes, int n_in,
                              void* d_out, int out_size, void* d_ws, size_t ws_size,
                              hipStream_t stream) {
    const float* pred_logits = (const float*)d_in[0];
    const float* pred_masks  = (const float*)d_in[1];
    const int*   tgt_labels  = (const int*)d_in[2];
    const float* tgt_masks   = (const float*)d_in[3];
    float* out = (float*)d_out;
    float* ws  = (float*)d_ws;

    hipMemsetAsync(d_ws, 0, 1024 * sizeof(float), stream);

    // grid: 128 chunks x (2 q-groups) x 4 batches = 1024 blocks of 4 waves
    partial_kernel<<<BS * 2 * NKB, 256, 0, stream>>>(pred_masks, tgt_masks, ws);
    finalize_kernel<<<BS * NQ, 256, 0, stream>>>(pred_logits, tgt_labels, ws, out);
}

// Round 14
// 38.274 us; speedup vs baseline: 1.9898x; 1.2294x over previous
//
#include <hip/hip_runtime.h>

#define BS 4
#define NQ 100
#define NT 25
#define NC 81
#define PIX 65536
#define KCHUNK 512
#define NKB (PIX / KCHUNK)       // 128 chunks per batch
#define STRY 520                 // LDS y row stride in ushorts (1040 B)
#define SLOT 432                 // per-(b,qt,chunk) slot: 400 xy|sy + 16 sp|sg + pad

// ws layout (floats): two partial arrays, no atomics, no zero-init needed
#define PSZ   (BS * 8 * NKB * SLOT)      // 1,769,472 floats
#define WS_P0 0                          // xy partials (+sp at 400; qt=7 slot: Sum_y at 0..25)
#define WS_P1 PSZ                        // sy partials (+sg at 400)

typedef __attribute__((ext_vector_type(8))) short bf16x8;
typedef __attribute__((ext_vector_type(4))) float f32x4;

__device__ __forceinline__ float4 ld4(const float* p) {
    return *reinterpret_cast<const float4*>(p);
}
__device__ __forceinline__ f32x4 mfma16(bf16x8 a, bf16x8 b, f32x4 c) {
    return __builtin_amdgcn_mfma_f32_16x16x32_bf16(a, b, c, 0, 0, 0);
}
// truncation pack: two f32 -> two bf16 in one u32 (1 op)
__device__ __forceinline__ unsigned pack2t(float lo, float hi) {
#if __has_builtin(__builtin_amdgcn_perm)
    return __builtin_amdgcn_perm(__float_as_uint(hi), __float_as_uint(lo), 0x07060302u);
#else
    return (__float_as_uint(hi) & 0xFFFF0000u) | (__float_as_uint(lo) >> 16);
#endif
}
// round-half-up pack (y staging only)
__device__ __forceinline__ unsigned pack2r(float lo, float hi) {
#if __has_builtin(__builtin_amdgcn_perm)
    return __builtin_amdgcn_perm(__float_as_uint(hi) + 0x8000u,
                                 __float_as_uint(lo) + 0x8000u, 0x07060302u);
#else
    return (((__float_as_uint(hi) + 0x8000u) & 0xFFFF0000u) |
            ((__float_as_uint(lo) + 0x8000u) >> 16));
#endif
}

union frag_u { unsigned u[4]; bf16x8 v; };

__global__ __launch_bounds__(256) void partial_kernel(
    const float* __restrict__ pm,   // [BS,NQ,PIX] mask logits
    const float* __restrict__ tm,   // [BS,NT,PIX] target masks
    float* __restrict__ ws)
{
    // 25 real rows; by1 lanes with lrow>=9 read a clamped row (their MFMA
    // columns t=25..31 are discarded at the C-store).
    __shared__ unsigned short ys[NT * STRY];   // 26.0 KB

    const int tid = threadIdx.x;
    const int bid = blockIdx.x;
    const int chunk = bid & (NKB - 1);
    const int rest = bid >> 7;       // 0..7
    const int qg = rest & 1;
    const int b = rest >> 1;
    const int kbase = chunk * KCHUNK;

    // ---- stage y chunk (25 rows) as bf16 ----
    {
        const float* yg = tm + (size_t)b * NT * PIX + kbase;
        for (int j = tid; j < NT * (KCHUNK / 4); j += 256) {
            const int row = j >> 7, c = j & 127;
            const float4 v = ld4(yg + (size_t)row * PIX + c * 4);
            uint2 w;
            w.x = pack2r(v.x, v.y);
            w.y = pack2r(v.z, v.w);
            *reinterpret_cast<uint2*>(&ys[row * STRY + c * 4]) = w;
        }
    }
    __syncthreads();

    const int l = tid & 63;
    const int wv = tid >> 6;
    const int qt = qg * 4 + wv;              // 0..7
    const bool ones_wave = (qt == 7);        // all q invalid -> Sum(y) duty
    const int lrow = l & 15;
    const int lk = (l >> 4) * 8;             // px offset of this lane's 8 elements
    const int r1 = (lrow < NT - 16) ? (16 + lrow) : lrow;   // clamped by1 row

    const int q = qt * 16 + lrow;
    const bool qv = (q < NQ);

    const float* xp = pm + (size_t)(b * NQ + (qv ? q : 0)) * PIX + kbase + lk;

    f32x4 cxy[2] = {};
    f32x4 csy[2] = {};
    float sx = 0.f, sg = 0.f, l2 = 0.f;

    frag_u fones;
    fones.u[0] = fones.u[1] = fones.u[2] = fones.u[3] = 0x3F803F80u;  // bf16 1.0 x2

    // ---- 2-deep x prefetch ring ----
    float4 Xa[2], Xb[2];
    if (!ones_wave) {
        Xa[0] = ld4(xp);      Xb[0] = ld4(xp + 4);
        Xa[1] = ld4(xp + 32); Xb[1] = ld4(xp + 36);
    }

    // ---- LDS y-frag prefetch, 1 k-step ahead ----
    bf16x8 by0 = *reinterpret_cast<const bf16x8*>(&ys[lrow * STRY + lk]);
    bf16x8 by1 = *reinterpret_cast<const bf16x8*>(&ys[r1 * STRY + lk]);

    #pragma unroll
    for (int kb = 0; kb < KCHUNK / 32; ++kb) {
        bf16x8 nb0, nb1;
        if (kb < KCHUNK / 32 - 1) {
            const int ko = (kb + 1) * 32;
            nb0 = *reinterpret_cast<const bf16x8*>(&ys[lrow * STRY + ko + lk]);
            nb1 = *reinterpret_cast<const bf16x8*>(&ys[r1 * STRY + ko + lk]);
        }

        frag_u fx, fs;
        if (!ones_wave) {
            const float4 xa = Xa[kb & 1], xb = Xb[kb & 1];
            if (kb < KCHUNK / 32 - 2) {
                const int ko = (kb + 2) * 32;
                Xa[kb & 1] = ld4(xp + ko);
                Xb[kb & 1] = ld4(xp + ko + 4);
            }
            // r = sigmoid(x) = 1/(1+e^{-x})
            // sum softplus = sum x - ln2 * log2(prod r)   (one log per 8 elems)
            const float xe[8] = {xa.x, xa.y, xa.z, xa.w, xb.x, xb.y, xb.z, xb.w};
            float rg[8];
            float pr = 1.0f;
            #pragma unroll
            for (int e = 0; e < 8; ++e) {
                const float x = xe[e];
                const float ex = __expf(-x);
                const float r = __builtin_amdgcn_rcpf(1.0f + ex);
                rg[e] = r;
                pr *= r;          // prod of 8 sigmoids: >= ~1e-35 for |x|<~10
                sx += x;
                sg += r;          // garbage on invalid-q lanes lands in unread slots
            }
            l2 += __log2f(pr);
            #pragma unroll
            for (int e = 0; e < 4; ++e) {
                fx.u[e] = pack2t(xe[2 * e], xe[2 * e + 1]);
                fs.u[e] = pack2t(rg[2 * e], rg[2 * e + 1]);
            }
        } else {
            fx = fones; fs = fones;
        }

        cxy[0] = mfma16(fx.v, by0, cxy[0]);
        cxy[1] = mfma16(fx.v, by1, cxy[1]);
        csy[0] = mfma16(fs.v, by0, csy[0]);
        csy[1] = mfma16(fs.v, by1, csy[1]);

        if (kb < KCHUNK / 32 - 1) { by0 = nb0; by1 = nb1; }
    }

    if (!ones_wave) {
        // ---- C partials + row sums -> plain stores, no atomics ----
        const size_t slot = ((size_t)(b * 8 + qt) * NKB + chunk) * SLOT;
        float* px = ws + WS_P0 + slot;
        float* ps = ws + WS_P1 + slot;
        #pragma unroll
        for (int n = 0; n < 2; ++n) {
            const int t = n * 16 + lrow;
            if (t < NT) {
                #pragma unroll
                for (int r = 0; r < 4; ++r) {
                    const int qr = (l >> 4) * 4 + r;
                    px[qr * NT + t] = cxy[n][r];
                    ps[qr * NT + t] = csy[n][r];
                }
            }
        }
        // row sums: lanes {l, l+16, l+32, l+48} share one q-row
        sx += __shfl_xor(sx, 16); sx += __shfl_xor(sx, 32);
        l2 += __shfl_xor(l2, 16); l2 += __shfl_xor(l2, 32);
        sg += __shfl_xor(sg, 16); sg += __shfl_xor(sg, 32);
        if (l < 16) {
            px[400 + l] = sx - 0.69314718056f * l2;   // softplus row-sum partial
            ps[400 + l] = sg;                          // sigma row-sum partial
        }
    } else {
        // A == ones -> every C row = sum_k y[t]; write Sum(y) slot (qt=7)
        const size_t slot7 = ((size_t)(b * 8 + 7) * NKB + chunk) * SLOT;
        float* p7 = ws + WS_P0 + slot7;
        if (l < 16) p7[l] = cxy[0][0];
        if (l < NT - 16) p7[16 + l] = cxy[1][0];
    }
}

__global__ __launch_bounds__(256) void finalize_kernel(
    const float* __restrict__ logits,  // [BS,NQ,NC]
    const int* __restrict__ labels,    // [BS,NT]
    const float* __restrict__ ws,
    float* __restrict__ out)           // [BS,NQ,NT]
{
    __shared__ float s1[256];
    __shared__ float s2[256];
    __shared__ float s3[256];
    __shared__ float s4[256];

    const int row = blockIdx.x;        // b*NQ + q
    const int b = row / NQ, q = row % NQ;
    const int qt = q / 16, qr = q % 16;
    const int tid = threadIdx.x;
    const int t = tid & 31, cg = tid >> 5;     // 8 chunk-groups

    const float* px = ws + WS_P0 + (size_t)(b * 8 + qt) * NKB * SLOT;
    const float* ps = ws + WS_P1 + (size_t)(b * 8 + qt) * NKB * SLOT;
    const float* p7 = ws + WS_P0 + (size_t)(b * 8 + 7) * NKB * SLOT;

    float a1 = 0.f, a2 = 0.f, a3 = 0.f, a4 = 0.f;
    if (t < NT) {
        #pragma unroll 4
        for (int k = 0; k < NKB / 8; ++k) {
            const size_t o = (size_t)(cg + 8 * k) * SLOT;
            a1 += px[o + qr * NT + t];     // xy partial
            a2 += ps[o + qr * NT + t];     // sy partial
            a3 += p7[o + t];               // Sum_y partial
        }
    } else if (t == 25) {
        #pragma unroll 4
        for (int k = 0; k < NKB / 8; ++k)
            a4 += px[(size_t)(cg + 8 * k) * SLOT + 400 + qr];   // softplus row sum
    } else if (t == 26) {
        #pragma unroll 4
        for (int k = 0; k < NKB / 8; ++k)
            a4 += ps[(size_t)(cg + 8 * k) * SLOT + 400 + qr];   // sigma row sum
    }
    s1[tid] = a1;
    s2[tid] = a2;
    s3[tid] = a3;
    s4[tid] = a4;
    __syncthreads();

    if (tid < 64) {
        const float* lg = logits + (size_t)row * NC;
        float v0 = (tid < NC) ? lg[tid] : -1e30f;
        float v1 = (tid + 64 < NC) ? lg[tid + 64] : -1e30f;
        float mx = fmaxf(v0, v1);
        #pragma unroll
        for (int off = 32; off; off >>= 1) mx = fmaxf(mx, __shfl_xor(mx, off, 64));
        float e = ((tid < NC) ? __expf(v0 - mx) : 0.f) +
                  ((tid + 64 < NC) ? __expf(v1 - mx) : 0.f);
        #pragma unroll
        for (int off = 32; off; off >>= 1) e += __shfl_xor(e, off, 64);

        if (tid < NT) {
            float xy = 0.f, sy = 0.f, yt = 0.f, sp = 0.f, sg = 0.f;
            #pragma unroll
            for (int g = 0; g < 8; ++g) {
                xy += s1[g * 32 + tid];
                sy += s2[g * 32 + tid];
                yt += s3[g * 32 + tid];
                sp += s4[g * 32 + 25];
                sg += s4[g * 32 + 26];
            }

            const int lab = labels[b * NT + tid];
            const float prob = __expf(lg[lab] - mx) / e;
            const float inv_p = 1.0f / (float)PIX;
            const float bce = sp * inv_p - xy * inv_p;
            const float dice = 1.0f - 2.0f * sy / (sg + yt + 1e-6f);
            out[(size_t)row * NT + tid] = -prob + bce + dice;
        }
    }
}

extern "C" void kernel_launch(void* const* d_in, const int* in_sizes, int n_in,
                              void* d_out, int out_size, void* d_ws, size_t ws_size,
                              hipStream_t stream) {
    const float* pred_logits = (const float*)d_in[0];
    const float* pred_masks  = (const float*)d_in[1];
    const int*   tgt_labels  = (const int*)d_in[2];
    const float* tgt_masks   = (const float*)d_in[3];
    float* out = (float*)d_out;
    float* ws  = (float*)d_ws;

    // No memset, no atomics: every location finalize reads is unconditionally
    // overwritten by partial_kernel each call.
    partial_kernel<<<BS * 2 * NKB, 256, 0, stream>>>(pred_masks, tgt_masks, ws);
    finalize_kernel<<<BS * NQ, 256, 0, stream>>>(pred_logits, tgt_labels, ws, out);
}